// Round 1
// baseline (601.010 us; speedup 1.0000x reference)
//
#include <hip/hip_runtime.h>
#include <math.h>

#define NC 10
#define NP 128
#define ND 512
#define GAMMA  0.1f
#define BCONST 10.0f
#define TAO    1.0f
#define LAMBDA 0.1f
#define THR2   1600.0f     // THRESHOLD^2 (compare d2 instead of sqrt(d2))
#define FEPS   1e-6f
#define NLDS   12          // proto slots 1..NLDS live in LDS; slot 0 in registers; >NLDS in global

__device__ __forceinline__ float allred64(float v) {
#pragma unroll
  for (int m = 1; m < 64; m <<= 1) v += __shfl_xor(v, m, 64);
  return v;
}

// ---------------------------------------------------------------------------
// Kernel 1: faithful sequential prototype assignment. One block per class.
// Phase 1 (256 thr): stable compaction of this class's sample indices -> LDS.
// Phase 2 (wave 0):  sequential scan with depth-3 feature prefetch.
// ---------------------------------------------------------------------------
__global__ __launch_bounds__(256)
void assign_kernel(const float* __restrict__ feats, const int* __restrict__ labels, int B,
                   float* __restrict__ gproto,   // [NC][NP][ND]
                   float* __restrict__ p2s,      // [NC*NP]  sum p^2
                   float* __restrict__ sps,      // [NC*NP]  sum p
                   int*   __restrict__ nproto_g) // [NC]
{
  __shared__ int   ls_list[8192];
  __shared__ int   ls_scan[256];
  __shared__ float ls_proto[NLDS][ND];
  __shared__ int   ls_cnt[NP];

  const int c = blockIdx.x;
  const int t = threadIdx.x;

  // ---- phase 1: stable partition (contiguous segments preserve order) ----
  const int segsz = (B + 255) >> 8;   // 32 for B=8192
  const int seg0  = t * segsz;
  int labv[32];
#pragma unroll
  for (int k = 0; k < 32; ++k) {
    int i = seg0 + k;
    labv[k] = (k < segsz && i < B) ? labels[i] : -1;
  }
  int cnt_local = 0;
#pragma unroll
  for (int k = 0; k < 32; ++k) cnt_local += (labv[k] == c) ? 1 : 0;

  ls_scan[t] = cnt_local;
  __syncthreads();
#pragma unroll
  for (int s = 1; s < 256; s <<= 1) {
    int v = (t >= s) ? ls_scan[t - s] : 0;
    __syncthreads();
    ls_scan[t] += v;
    __syncthreads();
  }
  int pos = ls_scan[t] - cnt_local;           // exclusive prefix
  const int cnt = ls_scan[255];               // samples in this class
#pragma unroll
  for (int k = 0; k < 32; ++k) {
    if (labv[k] == c) ls_list[pos++] = seg0 + k;
  }
  __syncthreads();

  if (t >= 64) return;                        // wave 0 continues; no more barriers
  const int lane = t;

  // ---- phase 2: sequential assignment ----
  float p0[8];                                // slot 0 prototype (register resident)
  int   cnt0 = 0;
  int   n = 0;
  float fA[8], fB[8], fC[8];

  auto LOADF = [&](float (&buf)[8], int m) {
    int idx = ls_list[m];
    const float4* fp = (const float4*)(feats + (size_t)idx * ND + lane * 8);
    float4 a = fp[0], b = fp[1];
    buf[0]=a.x; buf[1]=a.y; buf[2]=a.z; buf[3]=a.w;
    buf[4]=b.x; buf[5]=b.y; buf[6]=b.z; buf[7]=b.w;
  };

  auto STEP = [&](float (&f)[8]) {
    float best = 3.4e38f;
    int   bidx = 0;
    if (n > 0) {
      float part = 0.f;
#pragma unroll
      for (int e = 0; e < 8; ++e) { float d = f[e] - p0[e] + FEPS; part += d * d; }
      best = allred64(part);
      for (int j = 1; j < n; ++j) {           // rare path (n>1)
        float pj[8];
        if (j <= NLDS) {
          const float4* pp = (const float4*)(&ls_proto[j - 1][lane * 8]);
          float4 a = pp[0], b = pp[1];
          pj[0]=a.x; pj[1]=a.y; pj[2]=a.z; pj[3]=a.w;
          pj[4]=b.x; pj[5]=b.y; pj[6]=b.z; pj[7]=b.w;
        } else {
          const float4* pp = (const float4*)(gproto + ((size_t)c * NP + j) * ND + lane * 8);
          float4 a = pp[0], b = pp[1];
          pj[0]=a.x; pj[1]=a.y; pj[2]=a.z; pj[3]=a.w;
          pj[4]=b.x; pj[5]=b.y; pj[6]=b.z; pj[7]=b.w;
        }
        float part2 = 0.f;
#pragma unroll
        for (int e = 0; e < 8; ++e) { float d = f[e] - pj[e] + FEPS; part2 += d * d; }
        float tot = allred64(part2);
        if (tot < best) { best = tot; bidx = j; }   // strict < == first-min argmin
      }
    }
    if (n > 0 && best < THR2) {
      // running-mean update of closest prototype: (p*c + f) / (c+1)
      if (bidx == 0) {
        float cc  = (float)cnt0;
        float inv = 1.f / (cc + 1.f);
#pragma unroll
        for (int e = 0; e < 8; ++e) p0[e] = (p0[e] * cc + f[e]) * inv;
        cnt0++;
      } else {
        int   ci  = ls_cnt[bidx];
        float cc  = (float)ci;
        float inv = 1.f / (cc + 1.f);
        if (bidx <= NLDS) {
          float* row = &ls_proto[bidx - 1][lane * 8];
#pragma unroll
          for (int e = 0; e < 8; ++e) row[e] = (row[e] * cc + f[e]) * inv;
        } else {
          float* row = gproto + ((size_t)c * NP + bidx) * ND + lane * 8;
#pragma unroll
          for (int e = 0; e < 8; ++e) row[e] = (row[e] * cc + f[e]) * inv;
        }
        if (lane == 0) ls_cnt[bidx] = ci + 1;
      }
    } else {
      // append (also covers n==0)
      int app = min(n, NP - 1);
      if (app == 0) {
#pragma unroll
        for (int e = 0; e < 8; ++e) p0[e] = f[e];
        cnt0 = 1;
      } else if (app <= NLDS) {
        float* row = &ls_proto[app - 1][lane * 8];
#pragma unroll
        for (int e = 0; e < 8; ++e) row[e] = f[e];
        if (lane == 0) ls_cnt[app] = 1;
      } else {
        float* row = gproto + ((size_t)c * NP + app) * ND + lane * 8;
#pragma unroll
        for (int e = 0; e < 8; ++e) row[e] = f[e];
        if (lane == 0) ls_cnt[app] = 1;
      }
      n = min(n + 1, NP);
    }
  };

  if (cnt > 0) LOADF(fA, 0);
  if (cnt > 1) LOADF(fB, 1);
  if (cnt > 2) LOADF(fC, 2);
  int m = 0;
  while (m < cnt) {
    STEP(fA); ++m; if (m + 2 < cnt) LOADF(fA, m + 2);
    if (m >= cnt) break;
    STEP(fB); ++m; if (m + 2 < cnt) LOADF(fB, m + 2);
    if (m >= cnt) break;
    STEP(fC); ++m; if (m + 2 < cnt) LOADF(fC, m + 2);
  }

  // ---- epilogue: flush protos + per-proto sums for the loss kernel ----
  for (int j = 0; j < n; ++j) {
    float pj[8];
    if (j == 0) {
#pragma unroll
      for (int e = 0; e < 8; ++e) pj[e] = p0[e];
    } else if (j <= NLDS) {
      const float4* pp = (const float4*)(&ls_proto[j - 1][lane * 8]);
      float4 a = pp[0], b = pp[1];
      pj[0]=a.x; pj[1]=a.y; pj[2]=a.z; pj[3]=a.w;
      pj[4]=b.x; pj[5]=b.y; pj[6]=b.z; pj[7]=b.w;
    } else {
      const float4* pp = (const float4*)(gproto + ((size_t)c * NP + j) * ND + lane * 8);
      float4 a = pp[0], b = pp[1];
      pj[0]=a.x; pj[1]=a.y; pj[2]=a.z; pj[3]=a.w;
      pj[4]=b.x; pj[5]=b.y; pj[6]=b.z; pj[7]=b.w;
    }
    float4* gp = (float4*)(gproto + ((size_t)c * NP + j) * ND + lane * 8);
    float4 v0, v1;
    v0.x=pj[0]; v0.y=pj[1]; v0.z=pj[2]; v0.w=pj[3];
    v1.x=pj[4]; v1.y=pj[5]; v1.z=pj[6]; v1.w=pj[7];
    gp[0] = v0; gp[1] = v1;
    float P2p = 0.f, SPp = 0.f;
#pragma unroll
    for (int e = 0; e < 8; ++e) { P2p += pj[e] * pj[e]; SPp += pj[e]; }
    float P2 = allred64(P2p);
    float SP = allred64(SPp);
    if (lane == 0) { p2s[c * NP + j] = P2; sps[c * NP + j] = SP; }
  }
  if (lane == 0) nproto_g[c] = n;
}

// ---------------------------------------------------------------------------
// Kernel 2: loss. One wave per sample (grid-stride). Only valid prototypes
// contribute (masked terms are exactly zero / +inf in the reference).
// ---------------------------------------------------------------------------
__global__ __launch_bounds__(256)
void loss_kernel(const float* __restrict__ feats, const int* __restrict__ labels, int B,
                 const float* __restrict__ gproto, const float* __restrict__ p2s,
                 const float* __restrict__ sps, const int* __restrict__ nproto_g,
                 float* __restrict__ out)
{
  __shared__ float bsum[4];
  const int lane = threadIdx.x & 63;
  const int wid  = threadIdx.x >> 6;
  const int gw   = blockIdx.x * 4 + wid;
  const int nw   = gridDim.x * 4;

  int np[NC];
#pragma unroll
  for (int cc = 0; cc < NC; ++cc) np[cc] = nproto_g[cc];

  float acc = 0.f;
  for (int b = gw; b < B; b += nw) {
    const float4* fp = (const float4*)(feats + (size_t)b * ND + lane * 8);
    float4 a4 = fp[0], b4 = fp[1];
    float f[8] = {a4.x, a4.y, a4.z, a4.w, b4.x, b4.y, b4.z, b4.w};
    float f2p = 0.f, sfp = 0.f;
#pragma unroll
    for (int e = 0; e < 8; ++e) { f2p += f[e] * f[e]; sfp += f[e]; }
    float f2 = allred64(f2p);
    float sf = allred64(sfp);
    int lab = labels[b];

    float one = 0.f, num = 0.f, pw = 0.f;
    for (int cc = 0; cc < NC; ++cc) {
      int nn = np[cc];
      if (nn <= 0) continue;                 // class absent: no expv, no pairwise term
      float sume = 0.f, bestd2 = 3.4e38f;
      for (int j = 0; j < nn; ++j) {
        const float4* pp = (const float4*)(gproto + ((size_t)cc * NP + j) * ND + lane * 8);
        float4 pa = pp[0], pb = pp[1];
        float dp = f[0]*pa.x + f[1]*pa.y + f[2]*pa.z + f[3]*pa.w
                 + f[4]*pb.x + f[5]*pb.y + f[6]*pb.z + f[7]*pb.w;
        float dot = allred64(dp);
        float d2 = f2 + p2s[cc * NP + j] - 2.f * dot
                 + 2.f * FEPS * (sf - sps[cc * NP + j]) + (float)ND * FEPS * FEPS;
        d2 = fmaxf(d2, 0.f);
        sume  += expf(-GAMMA * d2);
        bestd2 = fminf(bestd2, d2);
      }
      one += sume;
      if (cc == lab) num = sume;
      float dmin = sqrtf(bestd2);
      float sign = (cc == lab) ? 1.f : -1.f;
      float z = BCONST - (TAO - dmin) * sign;
      float g = (z > 10.f) ? z : log1pf(expf(z));   // softplus, beta=1
      pw += g;
    }
    float prob = 1e-6f + ((one > 0.f) ? num / one : one);
    acc += -logf(prob) + LAMBDA * pw;
  }

  if (lane == 0) bsum[wid] = acc;
  __syncthreads();
  if (threadIdx.x == 0) atomicAdd(out, bsum[0] + bsum[1] + bsum[2] + bsum[3]);
}

// ---------------------------------------------------------------------------
extern "C" void kernel_launch(void* const* d_in, const int* in_sizes, int n_in,
                              void* d_out, int out_size, void* d_ws, size_t ws_size,
                              hipStream_t stream) {
  const float* feats  = (const float*)d_in[0];
  const int*   labels = (const int*)d_in[1];
  int B = in_sizes[0] / ND;   // 8192

  float* gproto   = (float*)d_ws;                 // NC*NP*ND floats
  float* p2s      = gproto + (size_t)NC * NP * ND;
  float* sps      = p2s + NC * NP;
  int*   nproto_g = (int*)(sps + NC * NP);

  hipMemsetAsync(d_out, 0, sizeof(float), stream);
  hipLaunchKernelGGL(assign_kernel, dim3(NC), dim3(256), 0, stream,
                     feats, labels, B, gproto, p2s, sps, nproto_g);
  hipLaunchKernelGGL(loss_kernel, dim3(1024), dim3(256), 0, stream,
                     feats, labels, B, gproto, p2s, sps, nproto_g, (float*)d_out);
}

// Round 2
// 119.591 us; speedup vs baseline: 5.0255x; 5.0255x over previous
//
#include <hip/hip_runtime.h>
#include <math.h>

#define NC 10
#define NP 128
#define ND 512
#define GAMMA  0.1f
#define BCONST 10.0f
#define TAO    1.0f
#define LAMBDA 0.1f
#define THR2   1600.0f     // THRESHOLD^2 (compare d2 instead of sqrt(d2))
#define FEPS   1e-6f
#define NLDS   12          // fallback: proto slots 1..NLDS in LDS; slot 0 in regs; rest global
#define CH     64          // speculation chunk size (== wave size)
#define MAXCH  128         // max chunks per class (covers all-8192-in-one-class)
#define IMAX   0x7FFFFFFF

__device__ __forceinline__ float allred64(float v) {
#pragma unroll
  for (int m = 1; m < 64; m <<= 1) v += __shfl_xor(v, m, 64);
  return v;
}

// ---------------------------------------------------------------------------
// A: stable per-class compaction -> global order list + class bases/counts.
// One block. Contiguous per-thread segments preserve original order.
// ---------------------------------------------------------------------------
__global__ __launch_bounds__(256)
void ord_kernel(const int* __restrict__ labels, int B,
                int* __restrict__ order, int* __restrict__ cls_base,
                int* __restrict__ cls_cnt, int* __restrict__ fail_pos)
{
  __shared__ int cnts[256][NC];
  __shared__ int tot_s[NC];
  __shared__ int base_s[NC];
  const int t = threadIdx.x;
  const int segsz = (B + 255) >> 8;
  const int s0 = t * segsz, s1 = min(s0 + segsz, B);

  int loc[NC];
#pragma unroll
  for (int c = 0; c < NC; ++c) loc[c] = 0;
  for (int i = s0; i < s1; ++i) loc[labels[i]]++;
#pragma unroll
  for (int c = 0; c < NC; ++c) cnts[t][c] = loc[c];
  __syncthreads();

  if (t < NC) {                       // exclusive scan over 256 threads, class t
    int run = 0;
    for (int i = 0; i < 256; ++i) { int v = cnts[i][t]; cnts[i][t] = run; run += v; }
    tot_s[t] = run;
  }
  __syncthreads();
  if (t < NC) {
    int b = 0;
    for (int c = 0; c < t; ++c) b += tot_s[c];
    base_s[t] = b;
    cls_base[t] = b;
    cls_cnt[t]  = tot_s[t];
    fail_pos[t] = IMAX;
  }
  __syncthreads();

  int pos[NC];
#pragma unroll
  for (int c = 0; c < NC; ++c) pos[c] = base_s[c] + cnts[t][c];
  for (int i = s0; i < s1; ++i) order[pos[labels[i]]++] = i;
}

// ---------------------------------------------------------------------------
// B: per-chunk feature sums. One wave per 64-sample chunk of a class.
// ---------------------------------------------------------------------------
__global__ __launch_bounds__(64)
void chunksum_kernel(const float* __restrict__ feats, const int* __restrict__ order,
                     const int* __restrict__ cls_base, const int* __restrict__ cls_cnt,
                     float* __restrict__ chunksum)
{
  const int c = blockIdx.x / MAXCH, g = blockIdx.x % MAXCH;
  const int cnt = cls_cnt[c];
  const int nch = (cnt + CH - 1) / CH;
  if (g >= nch) return;
  const int base = cls_base[c], lane = threadIdx.x;
  const int k0 = g * CH, k1 = min(k0 + CH, cnt);
  int myidx = (k0 + lane < cnt) ? order[base + k0 + lane] : 0;

  float S[8] = {0, 0, 0, 0, 0, 0, 0, 0};
  for (int k = k0; k < k1; ++k) {
    int idx = __shfl(myidx, k - k0, 64);
    const float4* fp = (const float4*)(feats + (size_t)idx * ND + lane * 8);
    float4 a = fp[0], b = fp[1];
    S[0]+=a.x; S[1]+=a.y; S[2]+=a.z; S[3]+=a.w;
    S[4]+=b.x; S[5]+=b.y; S[6]+=b.z; S[7]+=b.w;
  }
  float4* cp = (float4*)(chunksum + ((size_t)c * MAXCH + g) * ND + lane * 8);
  cp[0] = make_float4(S[0], S[1], S[2], S[3]);
  cp[1] = make_float4(S[4], S[5], S[6], S[7]);
}

// ---------------------------------------------------------------------------
// C: per-class exclusive scan of chunk sums (in place) + class total.
// ---------------------------------------------------------------------------
__global__ __launch_bounds__(64)
void chunkscan_kernel(const int* __restrict__ cls_cnt,
                      float* __restrict__ chunksum, float* __restrict__ totS)
{
  const int c = blockIdx.x, lane = threadIdx.x;
  const int cnt = cls_cnt[c];
  const int nch = (cnt + CH - 1) / CH;
  float run[8] = {0, 0, 0, 0, 0, 0, 0, 0};
  for (int g = 0; g < nch; ++g) {
    float4* cp = (float4*)(chunksum + ((size_t)c * MAXCH + g) * ND + lane * 8);
    float4 a = cp[0], b = cp[1];
    cp[0] = make_float4(run[0], run[1], run[2], run[3]);
    cp[1] = make_float4(run[4], run[5], run[6], run[7]);
    run[0]+=a.x; run[1]+=a.y; run[2]+=a.z; run[3]+=a.w;
    run[4]+=b.x; run[5]+=b.y; run[6]+=b.z; run[7]+=b.w;
  }
  float4* tp = (float4*)(totS + (size_t)c * ND + lane * 8);
  tp[0] = make_float4(run[0], run[1], run[2], run[3]);
  tp[1] = make_float4(run[4], run[5], run[6], run[7]);
}

// ---------------------------------------------------------------------------
// D: verify speculation. Running S is the only dependency chain (4cy/elem);
// d2 allreduces pipeline off the critical path. Any failure -> fail_pos[c].
// ---------------------------------------------------------------------------
__global__ __launch_bounds__(64)
void verify_kernel(const float* __restrict__ feats, const int* __restrict__ order,
                   const int* __restrict__ cls_base, const int* __restrict__ cls_cnt,
                   const float* __restrict__ chunksum, int* __restrict__ fail_pos)
{
  const int c = blockIdx.x / MAXCH, g = blockIdx.x % MAXCH;
  const int cnt = cls_cnt[c];
  const int nch = (cnt + CH - 1) / CH;
  if (g >= nch) return;
  const int base = cls_base[c], lane = threadIdx.x;
  const int k0 = g * CH, k1 = min(k0 + CH, cnt);
  int myidx = (k0 + lane < cnt) ? order[base + k0 + lane] : 0;

  const float4* cp = (const float4*)(chunksum + ((size_t)c * MAXCH + g) * ND + lane * 8);
  float4 a = cp[0], b = cp[1];
  float S[8] = {a.x, a.y, a.z, a.w, b.x, b.y, b.z, b.w};

  for (int k = k0; k < k1; ++k) {
    int idx = __shfl(myidx, k - k0, 64);
    const float4* fp = (const float4*)(feats + (size_t)idx * ND + lane * 8);
    float4 fa = fp[0], fb = fp[1];
    float f[8] = {fa.x, fa.y, fa.z, fa.w, fb.x, fb.y, fb.z, fb.w};
    if (k > 0) {
      float inv = 1.f / (float)k;       // mean over first k samples
      float part = 0.f;
#pragma unroll
      for (int e = 0; e < 8; ++e) { float d = f[e] - S[e] * inv + FEPS; part += d * d; }
      float d2 = allred64(part);
      if (!(d2 < THR2) && lane == 0) atomicMin(&fail_pos[c], k);
    }
#pragma unroll
    for (int e = 0; e < 8; ++e) S[e] += f[e];
  }
}

// ---------------------------------------------------------------------------
// E: finalize fast path: nproto=1, proto = totS/cnt, plus |p|^2 and sum(p).
// ---------------------------------------------------------------------------
__global__ __launch_bounds__(64)
void finalize_kernel(const int* __restrict__ cls_cnt, const int* __restrict__ fail_pos,
                     const float* __restrict__ totS, float* __restrict__ gproto,
                     float* __restrict__ p2s, float* __restrict__ sps,
                     int* __restrict__ nproto_g)
{
  const int c = blockIdx.x, lane = threadIdx.x;
  if (fail_pos[c] != IMAX) return;     // fallback kernel owns this class
  const int cnt = cls_cnt[c];
  if (cnt == 0) { if (lane == 0) nproto_g[c] = 0; return; }
  const float4* tp = (const float4*)(totS + (size_t)c * ND + lane * 8);
  float4 a = tp[0], b = tp[1];
  float inv = 1.f / (float)cnt;
  float p[8] = {a.x*inv, a.y*inv, a.z*inv, a.w*inv, b.x*inv, b.y*inv, b.z*inv, b.w*inv};
  float4* gp = (float4*)(gproto + (size_t)c * NP * ND + lane * 8);
  gp[0] = make_float4(p[0], p[1], p[2], p[3]);
  gp[1] = make_float4(p[4], p[5], p[6], p[7]);
  float P2p = 0.f, SPp = 0.f;
#pragma unroll
  for (int e = 0; e < 8; ++e) { P2p += p[e]*p[e]; SPp += p[e]; }
  float P2 = allred64(P2p), SP = allred64(SPp);
  if (lane == 0) { p2s[c*NP] = P2; sps[c*NP] = SP; nproto_g[c] = 1; }
}

// ---------------------------------------------------------------------------
// F: faithful sequential fallback — only runs for classes where speculation
// failed (never, on this data). One wave per class.
// ---------------------------------------------------------------------------
__global__ __launch_bounds__(64)
void fallback_kernel(const float* __restrict__ feats, const int* __restrict__ order,
                     const int* __restrict__ cls_base, const int* __restrict__ cls_cnt,
                     const int* __restrict__ fail_pos,
                     float* __restrict__ gproto, float* __restrict__ p2s,
                     float* __restrict__ sps, int* __restrict__ nproto_g)
{
  const int c = blockIdx.x;
  if (fail_pos[c] == IMAX) return;

  __shared__ float ls_proto[NLDS][ND];
  __shared__ int   ls_cnt[NP];
  const int lane = threadIdx.x;
  const int base = cls_base[c], cnt = cls_cnt[c];

  float p0[8];
  int cnt0 = 0, n = 0;
  float fA[8], fB[8], fC[8];

  auto LOADF = [&](float (&buf)[8], int m) {
    int idx = order[base + m];
    const float4* fp = (const float4*)(feats + (size_t)idx * ND + lane * 8);
    float4 a = fp[0], b = fp[1];
    buf[0]=a.x; buf[1]=a.y; buf[2]=a.z; buf[3]=a.w;
    buf[4]=b.x; buf[5]=b.y; buf[6]=b.z; buf[7]=b.w;
  };

  auto STEP = [&](float (&f)[8]) {
    float best = 3.4e38f;
    int bidx = 0;
    if (n > 0) {
      float part = 0.f;
#pragma unroll
      for (int e = 0; e < 8; ++e) { float d = f[e] - p0[e] + FEPS; part += d * d; }
      best = allred64(part);
      for (int j = 1; j < n; ++j) {
        float pj[8];
        if (j <= NLDS) {
          const float4* pp = (const float4*)(&ls_proto[j-1][lane*8]);
          float4 a = pp[0], b = pp[1];
          pj[0]=a.x; pj[1]=a.y; pj[2]=a.z; pj[3]=a.w;
          pj[4]=b.x; pj[5]=b.y; pj[6]=b.z; pj[7]=b.w;
        } else {
          const float4* pp = (const float4*)(gproto + ((size_t)c*NP + j)*ND + lane*8);
          float4 a = pp[0], b = pp[1];
          pj[0]=a.x; pj[1]=a.y; pj[2]=a.z; pj[3]=a.w;
          pj[4]=b.x; pj[5]=b.y; pj[6]=b.z; pj[7]=b.w;
        }
        float part2 = 0.f;
#pragma unroll
        for (int e = 0; e < 8; ++e) { float d = f[e] - pj[e] + FEPS; part2 += d * d; }
        float tot = allred64(part2);
        if (tot < best) { best = tot; bidx = j; }
      }
    }
    if (n > 0 && best < THR2) {
      if (bidx == 0) {
        float cc = (float)cnt0, inv = 1.f / (cc + 1.f);
#pragma unroll
        for (int e = 0; e < 8; ++e) p0[e] = (p0[e]*cc + f[e]) * inv;
        cnt0++;
      } else {
        int ci = ls_cnt[bidx];
        float cc = (float)ci, inv = 1.f / (cc + 1.f);
        if (bidx <= NLDS) {
          float* row = &ls_proto[bidx-1][lane*8];
#pragma unroll
          for (int e = 0; e < 8; ++e) row[e] = (row[e]*cc + f[e]) * inv;
        } else {
          float* row = gproto + ((size_t)c*NP + bidx)*ND + lane*8;
#pragma unroll
          for (int e = 0; e < 8; ++e) row[e] = (row[e]*cc + f[e]) * inv;
        }
        if (lane == 0) ls_cnt[bidx] = ci + 1;
      }
    } else {
      int app = min(n, NP - 1);
      if (app == 0) {
#pragma unroll
        for (int e = 0; e < 8; ++e) p0[e] = f[e];
        cnt0 = 1;
      } else if (app <= NLDS) {
        float* row = &ls_proto[app-1][lane*8];
#pragma unroll
        for (int e = 0; e < 8; ++e) row[e] = f[e];
        if (lane == 0) ls_cnt[app] = 1;
      } else {
        float* row = gproto + ((size_t)c*NP + app)*ND + lane*8;
#pragma unroll
        for (int e = 0; e < 8; ++e) row[e] = f[e];
        if (lane == 0) ls_cnt[app] = 1;
      }
      n = min(n + 1, NP);
    }
  };

  if (cnt > 0) LOADF(fA, 0);
  if (cnt > 1) LOADF(fB, 1);
  if (cnt > 2) LOADF(fC, 2);
  int m = 0;
  while (m < cnt) {
    STEP(fA); ++m; if (m + 2 < cnt) LOADF(fA, m + 2);
    if (m >= cnt) break;
    STEP(fB); ++m; if (m + 2 < cnt) LOADF(fB, m + 2);
    if (m >= cnt) break;
    STEP(fC); ++m; if (m + 2 < cnt) LOADF(fC, m + 2);
  }

  for (int j = 0; j < n; ++j) {
    float pj[8];
    if (j == 0) {
#pragma unroll
      for (int e = 0; e < 8; ++e) pj[e] = p0[e];
    } else if (j <= NLDS) {
      const float4* pp = (const float4*)(&ls_proto[j-1][lane*8]);
      float4 a = pp[0], b = pp[1];
      pj[0]=a.x; pj[1]=a.y; pj[2]=a.z; pj[3]=a.w;
      pj[4]=b.x; pj[5]=b.y; pj[6]=b.z; pj[7]=b.w;
    } else {
      const float4* pp = (const float4*)(gproto + ((size_t)c*NP + j)*ND + lane*8);
      float4 a = pp[0], b = pp[1];
      pj[0]=a.x; pj[1]=a.y; pj[2]=a.z; pj[3]=a.w;
      pj[4]=b.x; pj[5]=b.y; pj[6]=b.z; pj[7]=b.w;
    }
    float4* gp = (float4*)(gproto + ((size_t)c*NP + j)*ND + lane*8);
    gp[0] = make_float4(pj[0], pj[1], pj[2], pj[3]);
    gp[1] = make_float4(pj[4], pj[5], pj[6], pj[7]);
    float P2p = 0.f, SPp = 0.f;
#pragma unroll
    for (int e = 0; e < 8; ++e) { P2p += pj[e]*pj[e]; SPp += pj[e]; }
    float P2 = allred64(P2p), SP = allred64(SPp);
    if (lane == 0) { p2s[c*NP + j] = P2; sps[c*NP + j] = SP; }
  }
  if (lane == 0) nproto_g[c] = n;
}

// ---------------------------------------------------------------------------
// G: loss. One wave per sample (grid-stride); masked terms exact.
// ---------------------------------------------------------------------------
__global__ __launch_bounds__(256)
void loss_kernel(const float* __restrict__ feats, const int* __restrict__ labels, int B,
                 const float* __restrict__ gproto, const float* __restrict__ p2s,
                 const float* __restrict__ sps, const int* __restrict__ nproto_g,
                 float* __restrict__ out)
{
  __shared__ float bsum[4];
  const int lane = threadIdx.x & 63;
  const int wid  = threadIdx.x >> 6;
  const int gw   = blockIdx.x * 4 + wid;
  const int nw   = gridDim.x * 4;

  int np[NC];
#pragma unroll
  for (int cc = 0; cc < NC; ++cc) np[cc] = nproto_g[cc];

  float acc = 0.f;
  for (int b = gw; b < B; b += nw) {
    const float4* fp = (const float4*)(feats + (size_t)b * ND + lane * 8);
    float4 a4 = fp[0], b4 = fp[1];
    float f[8] = {a4.x, a4.y, a4.z, a4.w, b4.x, b4.y, b4.z, b4.w};
    float f2p = 0.f, sfp = 0.f;
#pragma unroll
    for (int e = 0; e < 8; ++e) { f2p += f[e]*f[e]; sfp += f[e]; }
    float f2 = allred64(f2p);
    float sf = allred64(sfp);
    int lab = labels[b];

    float one = 0.f, num = 0.f, pw = 0.f;
    for (int cc = 0; cc < NC; ++cc) {
      int nn = np[cc];
      if (nn <= 0) continue;
      float sume = 0.f, bestd2 = 3.4e38f;
      for (int j = 0; j < nn; ++j) {
        const float4* pp = (const float4*)(gproto + ((size_t)cc*NP + j)*ND + lane*8);
        float4 pa = pp[0], pb = pp[1];
        float dp = f[0]*pa.x + f[1]*pa.y + f[2]*pa.z + f[3]*pa.w
                 + f[4]*pb.x + f[5]*pb.y + f[6]*pb.z + f[7]*pb.w;
        float dot = allred64(dp);
        float d2 = f2 + p2s[cc*NP + j] - 2.f*dot
                 + 2.f*FEPS*(sf - sps[cc*NP + j]) + (float)ND*FEPS*FEPS;
        d2 = fmaxf(d2, 0.f);
        sume  += expf(-GAMMA * d2);
        bestd2 = fminf(bestd2, d2);
      }
      one += sume;
      if (cc == lab) num = sume;
      float dmin = sqrtf(bestd2);
      float sign = (cc == lab) ? 1.f : -1.f;
      float z = BCONST - (TAO - dmin) * sign;
      float g = (z > 10.f) ? z : log1pf(expf(z));
      pw += g;
    }
    float prob = 1e-6f + ((one > 0.f) ? num / one : one);
    acc += -logf(prob) + LAMBDA * pw;
  }

  if (lane == 0) bsum[wid] = acc;
  __syncthreads();
  if (threadIdx.x == 0) atomicAdd(out, bsum[0] + bsum[1] + bsum[2] + bsum[3]);
}

// ---------------------------------------------------------------------------
extern "C" void kernel_launch(void* const* d_in, const int* in_sizes, int n_in,
                              void* d_out, int out_size, void* d_ws, size_t ws_size,
                              hipStream_t stream) {
  const float* feats  = (const float*)d_in[0];
  const int*   labels = (const int*)d_in[1];
  int B = in_sizes[0] / ND;   // 8192

  float* gproto   = (float*)d_ws;                        // NC*NP*ND
  float* p2s      = gproto + (size_t)NC * NP * ND;       // NC*NP
  float* sps      = p2s + NC * NP;                       // NC*NP
  float* chunksum = sps + NC * NP;                       // NC*MAXCH*ND
  float* totS     = chunksum + (size_t)NC * MAXCH * ND;  // NC*ND
  int*   nproto_g = (int*)(totS + NC * ND);              // NC
  int*   order    = nproto_g + NC;                       // B
  int*   cls_base = order + B;                           // NC
  int*   cls_cnt  = cls_base + NC;                       // NC
  int*   fail_pos = cls_cnt + NC;                        // NC

  hipMemsetAsync(d_out, 0, sizeof(float), stream);
  hipLaunchKernelGGL(ord_kernel, dim3(1), dim3(256), 0, stream,
                     labels, B, order, cls_base, cls_cnt, fail_pos);
  hipLaunchKernelGGL(chunksum_kernel, dim3(NC * MAXCH), dim3(64), 0, stream,
                     feats, order, cls_base, cls_cnt, chunksum);
  hipLaunchKernelGGL(chunkscan_kernel, dim3(NC), dim3(64), 0, stream,
                     cls_cnt, chunksum, totS);
  hipLaunchKernelGGL(verify_kernel, dim3(NC * MAXCH), dim3(64), 0, stream,
                     feats, order, cls_base, cls_cnt, chunksum, fail_pos);
  hipLaunchKernelGGL(finalize_kernel, dim3(NC), dim3(64), 0, stream,
                     cls_cnt, fail_pos, totS, gproto, p2s, sps, nproto_g);
  hipLaunchKernelGGL(fallback_kernel, dim3(NC), dim3(64), 0, stream,
                     feats, order, cls_base, cls_cnt, fail_pos,
                     gproto, p2s, sps, nproto_g);
  hipLaunchKernelGGL(loss_kernel, dim3(1024), dim3(256), 0, stream,
                     feats, labels, B, gproto, p2s, sps, nproto_g, (float*)d_out);
}

// Round 3
// 92.674 us; speedup vs baseline: 6.4852x; 1.2904x over previous
//
#include <hip/hip_runtime.h>
#include <math.h>

#define NC 10
#define NP 128
#define ND 512
#define GAMMA  0.1f
#define BCONST 10.0f
#define TAO    1.0f
#define LAMBDA 0.1f
#define THR2   1600.0f     // THRESHOLD^2 (compare d2 instead of sqrt(d2))
#define FEPS   1e-6f
#define NLDS   12          // fallback: proto slots 1..NLDS in LDS; slot 0 in regs; rest global
#define CH     32          // speculation chunk size
#define MAXCH  256         // max chunks per class (covers all-8192-in-one-class)
#define IMAX   0x7FFFFFFF

__device__ __forceinline__ float allred64(float v) {
#pragma unroll
  for (int m = 1; m < 64; m <<= 1) v += __shfl_xor(v, m, 64);
  return v;
}

// ---------------------------------------------------------------------------
// A: stable per-class compaction -> order list + class bases/counts.
// One block, 256 threads. Coalesced label load -> LDS; Hillis-Steele scan.
// Also zeroes d_out (replaces the 42us in-graph fillBuffer).
// ---------------------------------------------------------------------------
__global__ __launch_bounds__(256)
void ord_kernel(const int* __restrict__ labels, int B,
                int* __restrict__ order, int* __restrict__ cls_base,
                int* __restrict__ cls_cnt, int* __restrict__ fail_pos,
                float* __restrict__ out)
{
  __shared__ int lab[8192];
  __shared__ int cnts[256][NC + 1];     // +1 pad: stride 11 (gcd 1 with 32 banks)
  __shared__ int tot_s[NC], base_s[NC];
  const int t = threadIdx.x;

  // coalesced label load into LDS
  const int4* lp = (const int4*)labels;
  for (int i = t; i < (B >> 2); i += 256) {
    int4 v = lp[i];
    lab[i*4+0] = v.x; lab[i*4+1] = v.y; lab[i*4+2] = v.z; lab[i*4+3] = v.w;
  }
  for (int i = (B & ~3) + t; i < B; i += 256) lab[i] = labels[i];
  __syncthreads();

  const int segsz = (B + 255) >> 8;
  const int s0 = t * segsz, s1 = min(s0 + segsz, B);

  int loc[NC];
#pragma unroll
  for (int c = 0; c < NC; ++c) loc[c] = 0;
  for (int i = s0; i < s1; ++i) {
    int l = lab[i];
#pragma unroll
    for (int c = 0; c < NC; ++c) loc[c] += (l == c) ? 1 : 0;
  }
#pragma unroll
  for (int c = 0; c < NC; ++c) cnts[t][c] = loc[c];
  __syncthreads();

  // inclusive Hillis-Steele scan across threads, vector of NC per thread
#pragma unroll
  for (int s = 1; s < 256; s <<= 1) {
    int v[NC];
#pragma unroll
    for (int c = 0; c < NC; ++c) v[c] = (t >= s) ? cnts[t - s][c] : 0;
    __syncthreads();
#pragma unroll
    for (int c = 0; c < NC; ++c) cnts[t][c] += v[c];
    __syncthreads();
  }

  if (t == 0) {
    int b = 0;
    for (int c = 0; c < NC; ++c) {
      int tc = cnts[255][c];
      base_s[c] = b; tot_s[c] = tc;
      cls_base[c] = b; cls_cnt[c] = tc; fail_pos[c] = IMAX;
      b += tc;
    }
    out[0] = 0.f;
  }
  __syncthreads();

  int pos[NC];
#pragma unroll
  for (int c = 0; c < NC; ++c) pos[c] = base_s[c] + cnts[t][c] - loc[c];
  for (int i = s0; i < s1; ++i) {
    int l = lab[i];
#pragma unroll
    for (int c = 0; c < NC; ++c)
      if (l == c) order[pos[c]++] = i;
  }
}

// ---------------------------------------------------------------------------
// B: per-chunk feature sums. One wave per 32-sample chunk; depth-4 pipeline.
// ---------------------------------------------------------------------------
__global__ __launch_bounds__(64)
void chunksum_kernel(const float* __restrict__ feats, const int* __restrict__ order,
                     const int* __restrict__ cls_base, const int* __restrict__ cls_cnt,
                     float* __restrict__ chunksum)
{
  const int c = blockIdx.x / MAXCH, g = blockIdx.x % MAXCH;
  const int cnt = cls_cnt[c];
  const int nch = (cnt + CH - 1) / CH;
  if (g >= nch) return;
  const int base = cls_base[c], lane = threadIdx.x;
  const int k0 = g * CH, k1 = min(k0 + CH, cnt);
  int myidx = (lane < CH && k0 + lane < cnt) ? order[base + k0 + lane] : 0;

  float S[8] = {0, 0, 0, 0, 0, 0, 0, 0};
  int k = k0;
  for (; k + 4 <= k1; k += 4) {
    float4 A[4], Bv[4];
#pragma unroll
    for (int j = 0; j < 4; ++j) {
      int idx = __shfl(myidx, k + j - k0, 64);
      const float4* fp = (const float4*)(feats + (size_t)idx * ND + lane * 8);
      A[j] = fp[0]; Bv[j] = fp[1];
    }
#pragma unroll
    for (int j = 0; j < 4; ++j) {
      S[0]+=A[j].x; S[1]+=A[j].y; S[2]+=A[j].z; S[3]+=A[j].w;
      S[4]+=Bv[j].x; S[5]+=Bv[j].y; S[6]+=Bv[j].z; S[7]+=Bv[j].w;
    }
  }
  for (; k < k1; ++k) {
    int idx = __shfl(myidx, k - k0, 64);
    const float4* fp = (const float4*)(feats + (size_t)idx * ND + lane * 8);
    float4 a = fp[0], b = fp[1];
    S[0]+=a.x; S[1]+=a.y; S[2]+=a.z; S[3]+=a.w;
    S[4]+=b.x; S[5]+=b.y; S[6]+=b.z; S[7]+=b.w;
  }
  float4* cp = (float4*)(chunksum + ((size_t)c * MAXCH + g) * ND + lane * 8);
  cp[0] = make_float4(S[0], S[1], S[2], S[3]);
  cp[1] = make_float4(S[4], S[5], S[6], S[7]);
}

// ---------------------------------------------------------------------------
// C: per-class exclusive scan of chunk sums (in place, dim-parallel across
// 256 threads) + unconditional speculative finalize (nproto=1, proto=mean).
// fallback_kernel overwrites everything for classes where speculation fails.
// ---------------------------------------------------------------------------
__global__ __launch_bounds__(256)
void scanfin_kernel(const int* __restrict__ cls_cnt,
                    float* __restrict__ chunksum, float* __restrict__ gproto,
                    float* __restrict__ p2s, float* __restrict__ sps,
                    int* __restrict__ nproto_g)
{
  __shared__ float red[8];
  const int c = blockIdx.x, t = threadIdx.x;
  const int cnt = cls_cnt[c];
  if (cnt == 0) { if (t == 0) nproto_g[c] = 0; return; }
  const int nch = (cnt + CH - 1) / CH;

  // thread t owns dims t and t+256; serial over chunks, coalesced columns.
  float* colA = chunksum + (size_t)c * MAXCH * ND + t;
  float* colB = colA + 256;
  float runA = 0.f, runB = 0.f;
  int g = 0;
  for (; g + 4 <= nch; g += 4) {
    float a0 = colA[(size_t)(g+0)*ND], b0 = colB[(size_t)(g+0)*ND];
    float a1 = colA[(size_t)(g+1)*ND], b1 = colB[(size_t)(g+1)*ND];
    float a2 = colA[(size_t)(g+2)*ND], b2 = colB[(size_t)(g+2)*ND];
    float a3 = colA[(size_t)(g+3)*ND], b3 = colB[(size_t)(g+3)*ND];
    colA[(size_t)(g+0)*ND] = runA;            colB[(size_t)(g+0)*ND] = runB;
    runA += a0; runB += b0;
    colA[(size_t)(g+1)*ND] = runA;            colB[(size_t)(g+1)*ND] = runB;
    runA += a1; runB += b1;
    colA[(size_t)(g+2)*ND] = runA;            colB[(size_t)(g+2)*ND] = runB;
    runA += a2; runB += b2;
    colA[(size_t)(g+3)*ND] = runA;            colB[(size_t)(g+3)*ND] = runB;
    runA += a3; runB += b3;
  }
  for (; g < nch; ++g) {
    float a = colA[(size_t)g*ND], b = colB[(size_t)g*ND];
    colA[(size_t)g*ND] = runA; colB[(size_t)g*ND] = runB;
    runA += a; runB += b;
  }

  // speculative prototype = class mean
  float inv = 1.f / (float)cnt;
  float pA = runA * inv, pB = runB * inv;
  gproto[(size_t)c * NP * ND + t]       = pA;
  gproto[(size_t)c * NP * ND + t + 256] = pB;

  // block-reduce p^2 and p over 512 dims
  float P2p = pA * pA + pB * pB;
  float SPp = pA + pB;
  float P2 = allred64(P2p), SP = allred64(SPp);
  const int lane = t & 63, wid = t >> 6;
  if (lane == 0) { red[wid] = P2; red[4 + wid] = SP; }
  __syncthreads();
  if (t == 0) {
    p2s[c * NP] = red[0] + red[1] + red[2] + red[3];
    sps[c * NP] = red[4] + red[5] + red[6] + red[7];
    nproto_g[c] = 1;
  }
}

// ---------------------------------------------------------------------------
// D: verify speculation. S-chain is the only dependency; loads run 4 deep.
// ---------------------------------------------------------------------------
__global__ __launch_bounds__(64)
void verify_kernel(const float* __restrict__ feats, const int* __restrict__ order,
                   const int* __restrict__ cls_base, const int* __restrict__ cls_cnt,
                   const float* __restrict__ chunksum, int* __restrict__ fail_pos)
{
  const int c = blockIdx.x / MAXCH, g = blockIdx.x % MAXCH;
  const int cnt = cls_cnt[c];
  const int nch = (cnt + CH - 1) / CH;
  if (g >= nch) return;
  const int base = cls_base[c], lane = threadIdx.x;
  const int k0 = g * CH, k1 = min(k0 + CH, cnt);
  int myidx = (lane < CH && k0 + lane < cnt) ? order[base + k0 + lane] : 0;

  const float4* cp = (const float4*)(chunksum + ((size_t)c * MAXCH + g) * ND + lane * 8);
  float4 a = cp[0], b = cp[1];
  float S[8] = {a.x, a.y, a.z, a.w, b.x, b.y, b.z, b.w};

  int k = k0;
  for (; k + 4 <= k1; k += 4) {
    float4 A[4], Bv[4];
#pragma unroll
    for (int j = 0; j < 4; ++j) {
      int idx = __shfl(myidx, k + j - k0, 64);
      const float4* fp = (const float4*)(feats + (size_t)idx * ND + lane * 8);
      A[j] = fp[0]; Bv[j] = fp[1];
    }
#pragma unroll
    for (int j = 0; j < 4; ++j) {
      int kk = k + j;
      float f[8] = {A[j].x, A[j].y, A[j].z, A[j].w, Bv[j].x, Bv[j].y, Bv[j].z, Bv[j].w};
      if (kk > 0) {
        float inv = 1.f / (float)kk;
        float part = 0.f;
#pragma unroll
        for (int e = 0; e < 8; ++e) { float d = f[e] - S[e] * inv + FEPS; part += d * d; }
        float d2 = allred64(part);
        if (!(d2 < THR2) && lane == 0) atomicMin(&fail_pos[c], kk);
      }
#pragma unroll
      for (int e = 0; e < 8; ++e) S[e] += f[e];
    }
  }
  for (; k < k1; ++k) {
    int idx = __shfl(myidx, k - k0, 64);
    const float4* fp = (const float4*)(feats + (size_t)idx * ND + lane * 8);
    float4 fa = fp[0], fb = fp[1];
    float f[8] = {fa.x, fa.y, fa.z, fa.w, fb.x, fb.y, fb.z, fb.w};
    if (k > 0) {
      float inv = 1.f / (float)k;
      float part = 0.f;
#pragma unroll
      for (int e = 0; e < 8; ++e) { float d = f[e] - S[e] * inv + FEPS; part += d * d; }
      float d2 = allred64(part);
      if (!(d2 < THR2) && lane == 0) atomicMin(&fail_pos[c], k);
    }
#pragma unroll
    for (int e = 0; e < 8; ++e) S[e] += f[e];
  }
}

// ---------------------------------------------------------------------------
// E: faithful sequential fallback — only for classes where speculation failed.
// ---------------------------------------------------------------------------
__global__ __launch_bounds__(64)
void fallback_kernel(const float* __restrict__ feats, const int* __restrict__ order,
                     const int* __restrict__ cls_base, const int* __restrict__ cls_cnt,
                     const int* __restrict__ fail_pos,
                     float* __restrict__ gproto, float* __restrict__ p2s,
                     float* __restrict__ sps, int* __restrict__ nproto_g)
{
  const int c = blockIdx.x;
  if (fail_pos[c] == IMAX) return;

  __shared__ float ls_proto[NLDS][ND];
  __shared__ int   ls_cnt[NP];
  const int lane = threadIdx.x;
  const int base = cls_base[c], cnt = cls_cnt[c];

  float p0[8];
  int cnt0 = 0, n = 0;
  float fA[8], fB[8], fC[8];

  auto LOADF = [&](float (&buf)[8], int m) {
    int idx = order[base + m];
    const float4* fp = (const float4*)(feats + (size_t)idx * ND + lane * 8);
    float4 a = fp[0], b = fp[1];
    buf[0]=a.x; buf[1]=a.y; buf[2]=a.z; buf[3]=a.w;
    buf[4]=b.x; buf[5]=b.y; buf[6]=b.z; buf[7]=b.w;
  };

  auto STEP = [&](float (&f)[8]) {
    float best = 3.4e38f;
    int bidx = 0;
    if (n > 0) {
      float part = 0.f;
#pragma unroll
      for (int e = 0; e < 8; ++e) { float d = f[e] - p0[e] + FEPS; part += d * d; }
      best = allred64(part);
      for (int j = 1; j < n; ++j) {
        float pj[8];
        if (j <= NLDS) {
          const float4* pp = (const float4*)(&ls_proto[j-1][lane*8]);
          float4 a = pp[0], b = pp[1];
          pj[0]=a.x; pj[1]=a.y; pj[2]=a.z; pj[3]=a.w;
          pj[4]=b.x; pj[5]=b.y; pj[6]=b.z; pj[7]=b.w;
        } else {
          const float4* pp = (const float4*)(gproto + ((size_t)c*NP + j)*ND + lane*8);
          float4 a = pp[0], b = pp[1];
          pj[0]=a.x; pj[1]=a.y; pj[2]=a.z; pj[3]=a.w;
          pj[4]=b.x; pj[5]=b.y; pj[6]=b.z; pj[7]=b.w;
        }
        float part2 = 0.f;
#pragma unroll
        for (int e = 0; e < 8; ++e) { float d = f[e] - pj[e] + FEPS; part2 += d * d; }
        float tot = allred64(part2);
        if (tot < best) { best = tot; bidx = j; }
      }
    }
    if (n > 0 && best < THR2) {
      if (bidx == 0) {
        float cc = (float)cnt0, inv = 1.f / (cc + 1.f);
#pragma unroll
        for (int e = 0; e < 8; ++e) p0[e] = (p0[e]*cc + f[e]) * inv;
        cnt0++;
      } else {
        int ci = ls_cnt[bidx];
        float cc = (float)ci, inv = 1.f / (cc + 1.f);
        if (bidx <= NLDS) {
          float* row = &ls_proto[bidx-1][lane*8];
#pragma unroll
          for (int e = 0; e < 8; ++e) row[e] = (row[e]*cc + f[e]) * inv;
        } else {
          float* row = gproto + ((size_t)c*NP + bidx)*ND + lane*8;
#pragma unroll
          for (int e = 0; e < 8; ++e) row[e] = (row[e]*cc + f[e]) * inv;
        }
        if (lane == 0) ls_cnt[bidx] = ci + 1;
      }
    } else {
      int app = min(n, NP - 1);
      if (app == 0) {
#pragma unroll
        for (int e = 0; e < 8; ++e) p0[e] = f[e];
        cnt0 = 1;
      } else if (app <= NLDS) {
        float* row = &ls_proto[app-1][lane*8];
#pragma unroll
        for (int e = 0; e < 8; ++e) row[e] = f[e];
        if (lane == 0) ls_cnt[app] = 1;
      } else {
        float* row = gproto + ((size_t)c*NP + app)*ND + lane*8;
#pragma unroll
        for (int e = 0; e < 8; ++e) row[e] = f[e];
        if (lane == 0) ls_cnt[app] = 1;
      }
      n = min(n + 1, NP);
    }
  };

  if (cnt > 0) LOADF(fA, 0);
  if (cnt > 1) LOADF(fB, 1);
  if (cnt > 2) LOADF(fC, 2);
  int m = 0;
  while (m < cnt) {
    STEP(fA); ++m; if (m + 2 < cnt) LOADF(fA, m + 2);
    if (m >= cnt) break;
    STEP(fB); ++m; if (m + 2 < cnt) LOADF(fB, m + 2);
    if (m >= cnt) break;
    STEP(fC); ++m; if (m + 2 < cnt) LOADF(fC, m + 2);
  }

  for (int j = 0; j < n; ++j) {
    float pj[8];
    if (j == 0) {
#pragma unroll
      for (int e = 0; e < 8; ++e) pj[e] = p0[e];
    } else if (j <= NLDS) {
      const float4* pp = (const float4*)(&ls_proto[j-1][lane*8]);
      float4 a = pp[0], b = pp[1];
      pj[0]=a.x; pj[1]=a.y; pj[2]=a.z; pj[3]=a.w;
      pj[4]=b.x; pj[5]=b.y; pj[6]=b.z; pj[7]=b.w;
    } else {
      const float4* pp = (const float4*)(gproto + ((size_t)c*NP + j)*ND + lane*8);
      float4 a = pp[0], b = pp[1];
      pj[0]=a.x; pj[1]=a.y; pj[2]=a.z; pj[3]=a.w;
      pj[4]=b.x; pj[5]=b.y; pj[6]=b.z; pj[7]=b.w;
    }
    float4* gp = (float4*)(gproto + ((size_t)c*NP + j)*ND + lane*8);
    gp[0] = make_float4(pj[0], pj[1], pj[2], pj[3]);
    gp[1] = make_float4(pj[4], pj[5], pj[6], pj[7]);
    float P2p = 0.f, SPp = 0.f;
#pragma unroll
    for (int e = 0; e < 8; ++e) { P2p += pj[e]*pj[e]; SPp += pj[e]; }
    float P2 = allred64(P2p), SP = allred64(SPp);
    if (lane == 0) { p2s[c*NP + j] = P2; sps[c*NP + j] = SP; }
  }
  if (lane == 0) nproto_g[c] = n;
}

// ---------------------------------------------------------------------------
// F: loss. One wave per sample; masked terms exact.
// ---------------------------------------------------------------------------
__global__ __launch_bounds__(256)
void loss_kernel(const float* __restrict__ feats, const int* __restrict__ labels, int B,
                 const float* __restrict__ gproto, const float* __restrict__ p2s,
                 const float* __restrict__ sps, const int* __restrict__ nproto_g,
                 float* __restrict__ out)
{
  __shared__ float bsum[4];
  const int lane = threadIdx.x & 63;
  const int wid  = threadIdx.x >> 6;
  const int gw   = blockIdx.x * 4 + wid;
  const int nw   = gridDim.x * 4;

  int np[NC];
#pragma unroll
  for (int cc = 0; cc < NC; ++cc) np[cc] = nproto_g[cc];

  float acc = 0.f;
  for (int b = gw; b < B; b += nw) {
    const float4* fp = (const float4*)(feats + (size_t)b * ND + lane * 8);
    float4 a4 = fp[0], b4 = fp[1];
    float f[8] = {a4.x, a4.y, a4.z, a4.w, b4.x, b4.y, b4.z, b4.w};
    float f2p = 0.f, sfp = 0.f;
#pragma unroll
    for (int e = 0; e < 8; ++e) { f2p += f[e]*f[e]; sfp += f[e]; }
    float f2 = allred64(f2p);
    float sf = allred64(sfp);
    int lab = labels[b];

    float one = 0.f, num = 0.f, pw = 0.f;
    for (int cc = 0; cc < NC; ++cc) {
      int nn = np[cc];
      if (nn <= 0) continue;
      float sume = 0.f, bestd2 = 3.4e38f;
      for (int j = 0; j < nn; ++j) {
        const float4* pp = (const float4*)(gproto + ((size_t)cc*NP + j)*ND + lane*8);
        float4 pa = pp[0], pb = pp[1];
        float dp = f[0]*pa.x + f[1]*pa.y + f[2]*pa.z + f[3]*pa.w
                 + f[4]*pb.x + f[5]*pb.y + f[6]*pb.z + f[7]*pb.w;
        float dot = allred64(dp);
        float d2 = f2 + p2s[cc*NP + j] - 2.f*dot
                 + 2.f*FEPS*(sf - sps[cc*NP + j]) + (float)ND*FEPS*FEPS;
        d2 = fmaxf(d2, 0.f);
        sume  += expf(-GAMMA * d2);
        bestd2 = fminf(bestd2, d2);
      }
      one += sume;
      if (cc == lab) num = sume;
      float dmin = sqrtf(bestd2);
      float sign = (cc == lab) ? 1.f : -1.f;
      float z = BCONST - (TAO - dmin) * sign;
      float g = (z > 10.f) ? z : log1pf(expf(z));
      pw += g;
    }
    float prob = 1e-6f + ((one > 0.f) ? num / one : one);
    acc += -logf(prob) + LAMBDA * pw;
  }

  if (lane == 0) bsum[wid] = acc;
  __syncthreads();
  if (threadIdx.x == 0) atomicAdd(out, bsum[0] + bsum[1] + bsum[2] + bsum[3]);
}

// ---------------------------------------------------------------------------
extern "C" void kernel_launch(void* const* d_in, const int* in_sizes, int n_in,
                              void* d_out, int out_size, void* d_ws, size_t ws_size,
                              hipStream_t stream) {
  const float* feats  = (const float*)d_in[0];
  const int*   labels = (const int*)d_in[1];
  int B = in_sizes[0] / ND;   // 8192

  float* gproto   = (float*)d_ws;                        // NC*NP*ND
  float* p2s      = gproto + (size_t)NC * NP * ND;       // NC*NP
  float* sps      = p2s + NC * NP;                       // NC*NP
  float* chunksum = sps + NC * NP;                       // NC*MAXCH*ND
  int*   nproto_g = (int*)(chunksum + (size_t)NC * MAXCH * ND); // NC
  int*   order    = nproto_g + NC;                       // B
  int*   cls_base = order + B;                           // NC
  int*   cls_cnt  = cls_base + NC;                       // NC
  int*   fail_pos = cls_cnt + NC;                        // NC

  hipLaunchKernelGGL(ord_kernel, dim3(1), dim3(256), 0, stream,
                     labels, B, order, cls_base, cls_cnt, fail_pos, (float*)d_out);
  hipLaunchKernelGGL(chunksum_kernel, dim3(NC * MAXCH), dim3(64), 0, stream,
                     feats, order, cls_base, cls_cnt, chunksum);
  hipLaunchKernelGGL(scanfin_kernel, dim3(NC), dim3(256), 0, stream,
                     cls_cnt, chunksum, gproto, p2s, sps, nproto_g);
  hipLaunchKernelGGL(verify_kernel, dim3(NC * MAXCH), dim3(64), 0, stream,
                     feats, order, cls_base, cls_cnt, chunksum, fail_pos);
  hipLaunchKernelGGL(fallback_kernel, dim3(NC), dim3(64), 0, stream,
                     feats, order, cls_base, cls_cnt, fail_pos,
                     gproto, p2s, sps, nproto_g);
  hipLaunchKernelGGL(loss_kernel, dim3(2048), dim3(256), 0, stream,
                     feats, labels, B, gproto, p2s, sps, nproto_g, (float*)d_out);
}